// Round 6
// baseline (151.725 us; speedup 1.0000x reference)
//
#include <hip/hip_runtime.h>
#include <hip/hip_bf16.h>

// Problem constants
#define BATCH 8
#define TLEN 2048
#define CDIM 1024
#define HDIM 64
#define BT (BATCH * TLEN)   // 16384

typedef __attribute__((ext_vector_type(8))) short short8;
typedef __attribute__((ext_vector_type(4))) float f32x4;

#define GLOAD16(gsrc, lds) __builtin_amdgcn_global_load_lds( \
    (const __attribute__((address_space(1))) void*)(gsrc),   \
    (__attribute__((address_space(3))) void*)(lds), 16, 0, 0)

#if __has_builtin(__builtin_amdgcn_exp2f)
#define EXP2(x) __builtin_amdgcn_exp2f(x)
#else
#define EXP2(x) exp2f(x)
#endif

// round-to-nearest-even f32 -> bf16 (bit pattern)
__device__ inline unsigned bfbits(float f) {
    unsigned u = __builtin_bit_cast(unsigned, f);
    return (u + 0x7fffu + ((u >> 16) & 1u)) >> 16;
}
__device__ inline short bf1(float f) { return (short)bfbits(f); }
// packed f32x2 -> bf16x2 via HW instruction (src0 -> low half)
__device__ inline unsigned cvtpk(float lo, float hi) {
    unsigned r;
    asm("v_cvt_pk_bf16_f32 %0, %1, %2" : "=v"(r) : "v"(lo), "v"(hi));
    return r;
}

// ---------------------------------------------------------------------------
// Kernel 0: transpose + bf16-cast weights. Wt[3][64 n][1024 k] = W[k][n].
// Folds attention scale AND log2(e) into Wq: 0.125 * 1.4426950 (softmax is
// computed in base 2 with native v_exp_f32).
// ---------------------------------------------------------------------------
__global__ __launch_bounds__(256) void wt_kernel(
        const float* __restrict__ Wq, const float* __restrict__ Wk,
        const float* __restrict__ Wv, short* __restrict__ Wt) {
    const int kc = blockIdx.x * 64;
    const int wi = blockIdx.y;
    const float* W = (wi == 0) ? Wq : ((wi == 1) ? Wk : Wv);
    const float scale = (wi == 0) ? 0.125f * 1.44269504088896f : 1.0f;
    __shared__ short tile[64][65];
    const int t = threadIdx.x;
    #pragma unroll
    for (int i = 0; i < 16; ++i) {
        int flat = i * 256 + t;
        int kk = flat >> 6, n = flat & 63;
        tile[kk][n] = bf1(W[(size_t)(kc + kk) * HDIM + n] * scale);
    }
    __syncthreads();
    const int n = t >> 2, c0 = (t & 3) * 16;
    #pragma unroll
    for (int i = 0; i < 16; ++i)
        Wt[((size_t)wi * 64 + n) * CDIM + kc + c0 + i] = tile[c0 + i][n];
}

// ---------------------------------------------------------------------------
// Kernel 1: QKV projection, 32 rows/block (512 blocks), 2-phase pipelined:
// double-buffered LDS, stage(next) issued BEFORE compute(cur), one barrier
// per K-step so global_load_lds latency hides under MFMA + cvt_pk.
// Outputs: Q,K row-major [t][64]; V transposed Vt[b][h][t].
// ---------------------------------------------------------------------------
__global__ __launch_bounds__(256) void qkv_kernel(
        const float* __restrict__ x, const short* __restrict__ Wt,
        short* __restrict__ Q, short* __restrict__ K, short* __restrict__ Vt) {
    __shared__ float xs[2][32 * 64];      // 2 x 8 KB, swizzled
    __shared__ short wl[2][3 * 64 * 64];  // 2 x 24 KB, swizzled
    __shared__ short ob[32 * 72];         // epilogue staging (padded)
    const int t = threadIdx.x;
    const int lane = t & 63, w = t >> 6;
    const int lr = lane & 15, lg = lane >> 4;
    const int r0 = blockIdx.x * 32;

    auto stage = [&](int buf, int kc) {
        #pragma unroll
        for (int i = 0; i < 2; ++i) {
            int chunk = t + 256 * i;
            int row = chunk >> 4, slot = chunk & 15;
            GLOAD16(x + (size_t)(r0 + row) * CDIM + kc + ((slot ^ (row & 7)) << 2),
                    xs[buf] + chunk * 4);
        }
        #pragma unroll
        for (int i = 0; i < 6; ++i) {
            int chunk = t + 256 * i;
            int R = chunk >> 3, slot = chunk & 7;
            GLOAD16(Wt + (size_t)R * CDIM + kc + ((slot ^ (R & 7)) << 3),
                    wl[buf] + chunk * 8);
        }
    };

    f32x4 acc[3][2];
    #pragma unroll
    for (int wi = 0; wi < 3; ++wi)
        #pragma unroll
        for (int rt = 0; rt < 2; ++rt) acc[wi][rt] = f32x4{0.f, 0.f, 0.f, 0.f};

    stage(0, 0);
    int cur = 0;
    for (int kc = 0; kc < CDIM; kc += 64) {
        __syncthreads();                       // drains prior stage (vmcnt(0))
        if (kc + 64 < CDIM) stage(cur ^ 1, kc + 64);   // in flight during compute
        const float* xsc = xs[cur];
        const short* wlc = wl[cur];

        short8 af[2][2];
        #pragma unroll
        for (int rt = 0; rt < 2; ++rt)
            #pragma unroll
            for (int ks = 0; ks < 2; ++ks) {
                int row = rt * 16 + lr;
                int s0 = ks * 8 + lg * 2;
                f32x4 a0 = *(const f32x4*)(xsc + row * 64 + (((s0)     ^ (row & 7)) << 2));
                f32x4 a1 = *(const f32x4*)(xsc + row * 64 + (((s0 + 1) ^ (row & 7)) << 2));
                uint4 uu;
                uu.x = cvtpk(a0[0], a0[1]); uu.y = cvtpk(a0[2], a0[3]);
                uu.z = cvtpk(a1[0], a1[1]); uu.w = cvtpk(a1[2], a1[3]);
                af[rt][ks] = __builtin_bit_cast(short8, uu);
            }
        #pragma unroll
        for (int wi = 0; wi < 3; ++wi)
            #pragma unroll
            for (int ks = 0; ks < 2; ++ks) {
                int R = wi * 64 + w * 16 + lr;
                short8 bfv = *(const short8*)(wlc + R * 64 + (((ks * 4 + lg) ^ (lr & 7)) << 3));
                #pragma unroll
                for (int rt = 0; rt < 2; ++rt)
                    acc[wi][rt] = __builtin_amdgcn_mfma_f32_16x16x32_bf16(
                        af[rt][ks], bfv, acc[wi][rt], 0, 0, 0);
            }
        cur ^= 1;
    }
    // V epilogue: C/D rows are consecutive t -> pack pairs, 8B stores to Vt[b][h][t]
    {
        const int bb = r0 >> 11, t0 = r0 & 2047;
        #pragma unroll
        for (int rt = 0; rt < 2; ++rt) {
            uint2 uv;
            uv.x = cvtpk(acc[2][rt][0], acc[2][rt][1]);
            uv.y = cvtpk(acc[2][rt][2], acc[2][rt][3]);
            *(uint2*)(Vt + ((size_t)bb * HDIM + w * 16 + lr) * TLEN + t0 + rt * 16 + lg * 4) = uv;
        }
    }
    // Q, K epilogue via LDS transpose -> coalesced short8 stores
    #pragma unroll
    for (int wi = 0; wi < 2; ++wi) {
        __syncthreads();
        #pragma unroll
        for (int rt = 0; rt < 2; ++rt)
            #pragma unroll
            for (int i = 0; i < 4; ++i)
                ob[(rt * 16 + lg * 4 + i) * 72 + w * 16 + lr] = bf1(acc[wi][rt][i]);
        __syncthreads();
        int row = t >> 3, c0 = (t & 7) * 8;
        short8 v = *(short8*)(ob + row * 72 + c0);
        short* dst = (wi == 0) ? Q : K;
        *(short8*)(dst + (size_t)(r0 + row) * HDIM + c0) = v;
    }
}

// ---------------------------------------------------------------------------
// Kernel 2: flash attention, causal, swapped QK^T (S^T = mfma(K, Q)),
// base-2 softmax (log2e folded into Wq upstream).
// One 16-row q-tile per block, 1024 blocks = 4 blocks/CU = 4 waves/SIMD.
// All 4 waves split the tile's kv supertiles 4-way (s = w, w+4, ...) with
// no barriers in the loop; 4 partial (m,l,O^T) states merge once via LDS.
// qi = 127 - blockIdx.y: heavy tiles dispatch first, light ones backfill.
// Per-lane state is for q-row = lane&15: softmax in-lane + 2 shfl_xor;
// O accumulated as O^T (mfma(Vt, P)) so rescale/normalize are in-lane.
// V loads issue after QK so their latency hides under softmax + P pack.
// ---------------------------------------------------------------------------
__global__ __launch_bounds__(256, 4) void attn_kernel(
        const short* __restrict__ Q, const short* __restrict__ K,
        const short* __restrict__ Vt, float* __restrict__ O) {
    __shared__ short Ps[4][16 * 64];   // per-wave P buffer, XOR-swizzled
    __shared__ float Om[4][16 * 68];   // per-wave [q][h] partials, padded
    __shared__ float ml[4][2][16];     // per-wave {m,l}[q]
    const int t = threadIdx.x, lane = t & 63, w = t >> 6;
    const int lr = lane & 15, lg = lane >> 4;
    const int b = blockIdx.x;
    const int qi = (TLEN / 16 - 1) - blockIdx.y;   // descending: heavy first
    const int q0 = qi * 16;
    const size_t base = (size_t)b * TLEN * HDIM;
    const short* Kb = K + base;
    const short* Vb = Vt + base;    // same per-batch stride (64*2048)
    char* myPs = (char*)Ps[w];
    const int swz = (lr & 7) << 4;  // byte XOR within 128B row
    const int nsup = (q0 + 79) >> 6;

    // Q B-operand fragments: col = q = lr, k = h
    short8 qf0 = *(const short8*)(Q + base + (size_t)(q0 + lr) * HDIM + lg * 8);
    short8 qf1 = *(const short8*)(Q + base + (size_t)(q0 + lr) * HDIM + 32 + lg * 8);

    f32x4 o[4];
    #pragma unroll
    for (int ht = 0; ht < 4; ++ht) o[ht] = f32x4{0.f, 0.f, 0.f, 0.f};
    float m = -1e30f, l = 0.f;

    for (int s = w; s < nsup; s += 4) {
        const int kv0 = s * 64;
        // K fragments (A-operand rows = kv)
        short8 kf[8];
        #pragma unroll
        for (int h2 = 0; h2 < 2; ++h2)
            #pragma unroll
            for (int kt = 0; kt < 2; ++kt) {
                const short* kp = Kb + (size_t)(kv0 + h2 * 32 + kt * 16 + lr) * HDIM + lg * 8;
                kf[(h2 * 2 + kt) * 2]     = *(const short8*)kp;
                kf[(h2 * 2 + kt) * 2 + 1] = *(const short8*)(kp + 32);
            }
        // S^T = K Q^T : rows = kv, cols = q (already in log2 units)
        f32x4 st[2][2];
        #pragma unroll
        for (int h2 = 0; h2 < 2; ++h2)
            #pragma unroll
            for (int kt = 0; kt < 2; ++kt) {
                f32x4 a = f32x4{0.f, 0.f, 0.f, 0.f};
                a = __builtin_amdgcn_mfma_f32_16x16x32_bf16(kf[(h2*2+kt)*2],     qf0, a, 0, 0, 0);
                a = __builtin_amdgcn_mfma_f32_16x16x32_bf16(kf[(h2*2+kt)*2 + 1], qf1, a, 0, 0, 0);
                st[h2][kt] = a;
            }
        // V loads issue now; latency hides under softmax + P pack
        short8 vf[8];
        #pragma unroll
        for (int h2 = 0; h2 < 2; ++h2)
            #pragma unroll
            for (int ht = 0; ht < 4; ++ht)
                vf[h2 * 4 + ht] = *(const short8*)(
                    Vb + (size_t)(ht * 16 + lr) * TLEN + kv0 + h2 * 32 + lg * 8);
        if (s == nsup - 1) {              // diagonal supertile: mask kv > q
            const int q = q0 + lr;
            #pragma unroll
            for (int h2 = 0; h2 < 2; ++h2)
                #pragma unroll
                for (int kt = 0; kt < 2; ++kt)
                    #pragma unroll
                    for (int i = 0; i < 4; ++i)
                        if (kv0 + h2 * 32 + kt * 16 + lg * 4 + i > q)
                            st[h2][kt][i] = -1e30f;
        }
        // online softmax (base 2) for q-row lr: in-lane over 16 vals + 2 shfl
        float tm = -1e30f;
        #pragma unroll
        for (int h2 = 0; h2 < 2; ++h2)
            #pragma unroll
            for (int kt = 0; kt < 2; ++kt)
                #pragma unroll
                for (int i = 0; i < 4; ++i) tm = fmaxf(tm, st[h2][kt][i]);
        tm = fmaxf(tm, __shfl_xor(tm, 16));
        tm = fmaxf(tm, __shfl_xor(tm, 32));
        float mn = fmaxf(m, tm);
        float fs = EXP2(m - mn);
        m = mn;
        float ls = 0.f;
        #pragma unroll
        for (int h2 = 0; h2 < 2; ++h2)
            #pragma unroll
            for (int kt = 0; kt < 2; ++kt)
                #pragma unroll
                for (int i = 0; i < 4; ++i) {
                    float e = EXP2(st[h2][kt][i] - mn);
                    st[h2][kt][i] = e;
                    ls += e;
                }
        ls += __shfl_xor(ls, 16);
        ls += __shfl_xor(ls, 32);
        l = l * fs + ls;
        #pragma unroll
        for (int ht = 0; ht < 4; ++ht)
            #pragma unroll
            for (int i = 0; i < 4; ++i) o[ht][i] *= fs;
        // pack P -> per-wave swizzled LDS (row = q = lr), then B-frag reads
        #pragma unroll
        for (int h2 = 0; h2 < 2; ++h2)
            #pragma unroll
            for (int kt = 0; kt < 2; ++kt) {
                uint2 u;
                u.x = cvtpk(st[h2][kt][0], st[h2][kt][1]);
                u.y = cvtpk(st[h2][kt][2], st[h2][kt][3]);
                *(uint2*)(myPs + lr * 128 + ((h2 * 64 + kt * 32 + lg * 8) ^ swz)) = u;
            }
        short8 pb0 = *(short8*)(myPs + lr * 128 + ((lg * 16) ^ swz));
        short8 pb1 = *(short8*)(myPs + lr * 128 + ((64 + lg * 16) ^ swz));
        // O^T += V^T P
        #pragma unroll
        for (int h2 = 0; h2 < 2; ++h2) {
            short8 pb = h2 ? pb1 : pb0;
            #pragma unroll
            for (int ht = 0; ht < 4; ++ht)
                o[ht] = __builtin_amdgcn_mfma_f32_16x16x32_bf16(
                    vf[h2 * 4 + ht], pb, o[ht], 0, 0, 0);
        }
    }
    // write partial state
    {
        float* om = Om[w];
        #pragma unroll
        for (int ht = 0; ht < 4; ++ht)
            *(f32x4*)(om + lr * 68 + ht * 16 + lg * 4) = o[ht];
        if (lg == 0) {
            ml[w][0][lr] = m;
            ml[w][1][lr] = l;
        }
    }
    __syncthreads();
    // merge 4 partials: thread (w,lane) handles q = lr, h = w*16 + lg*4 ..
    {
        float mp[4], fp[4];
        float mm = -1e30f;
        #pragma unroll
        for (int p = 0; p < 4; ++p) { mp[p] = ml[p][0][lr]; mm = fmaxf(mm, mp[p]); }
        float lsum = 0.f;
        #pragma unroll
        for (int p = 0; p < 4; ++p) {
            fp[p] = EXP2(mp[p] - mm);
            lsum += ml[p][1][lr] * fp[p];
        }
        float inv = 1.0f / lsum;
        const int off = lr * 68 + w * 16 + lg * 4;
        f32x4 r = f32x4{0.f, 0.f, 0.f, 0.f};
        #pragma unroll
        for (int p = 0; p < 4; ++p) {
            f32x4 v = *(const f32x4*)(&Om[p][off]);
            #pragma unroll
            for (int i = 0; i < 4; ++i) r[i] += v[i] * fp[p];
        }
        #pragma unroll
        for (int i = 0; i < 4; ++i) r[i] *= inv;
        *(f32x4*)(O + base + (size_t)(q0 + lr) * HDIM + w * 16 + lg * 4) = r;
    }
}

// ---------------------------------------------------------------------------
extern "C" void kernel_launch(void* const* d_in, const int* in_sizes, int n_in,
                              void* d_out, int out_size, void* d_ws, size_t ws_size,
                              hipStream_t stream) {
    const float* x  = (const float*)d_in[0];
    const float* Wq = (const float*)d_in[1];
    const float* Wk = (const float*)d_in[2];
    const float* Wv = (const float*)d_in[3];
    float* out = (float*)d_out;

    char* ws = (char*)d_ws;
    short* Q  = (short*)(ws);
    short* K  = (short*)(ws + (size_t)2 * 1024 * 1024);
    short* Vt = (short*)(ws + (size_t)4 * 1024 * 1024);
    short* Wt = (short*)(ws + (size_t)6 * 1024 * 1024);

    wt_kernel<<<dim3(16, 3), 256, 0, stream>>>(Wq, Wk, Wv, Wt);
    qkv_kernel<<<BT / 32, 256, 0, stream>>>(x, Wt, Q, K, Vt);
    attn_kernel<<<dim3(BATCH, TLEN / 16), 256, 0, stream>>>(Q, K, Vt, out);
}

// Round 7
// 150.285 us; speedup vs baseline: 1.0096x; 1.0096x over previous
//
#include <hip/hip_runtime.h>
#include <hip/hip_bf16.h>

// Problem constants
#define BATCH 8
#define TLEN 2048
#define CDIM 1024
#define HDIM 64
#define BT (BATCH * TLEN)   // 16384

typedef __attribute__((ext_vector_type(8))) short short8;
typedef __attribute__((ext_vector_type(4))) float f32x4;

#define GLOAD16(gsrc, lds) __builtin_amdgcn_global_load_lds( \
    (const __attribute__((address_space(1))) void*)(gsrc),   \
    (__attribute__((address_space(3))) void*)(lds), 16, 0, 0)

#if __has_builtin(__builtin_amdgcn_exp2f)
#define EXP2(x) __builtin_amdgcn_exp2f(x)
#else
#define EXP2(x) exp2f(x)
#endif

// round-to-nearest-even f32 -> bf16 (bit pattern)
__device__ inline unsigned bfbits(float f) {
    unsigned u = __builtin_bit_cast(unsigned, f);
    return (u + 0x7fffu + ((u >> 16) & 1u)) >> 16;
}
__device__ inline short bf1(float f) { return (short)bfbits(f); }
// packed f32x2 -> bf16x2 via HW instruction (src0 -> low half)
__device__ inline unsigned cvtpk(float lo, float hi) {
    unsigned r;
    asm("v_cvt_pk_bf16_f32 %0, %1, %2" : "=v"(r) : "v"(lo), "v"(hi));
    return r;
}

// ---------------------------------------------------------------------------
// Kernel 0: transpose + bf16-cast weights. Wt[3][64 n][1024 k] = W[k][n].
// Folds attention scale AND log2(e) into Wq (softmax runs in base 2).
// ---------------------------------------------------------------------------
__global__ __launch_bounds__(256) void wt_kernel(
        const float* __restrict__ Wq, const float* __restrict__ Wk,
        const float* __restrict__ Wv, short* __restrict__ Wt) {
    const int kc = blockIdx.x * 64;
    const int wi = blockIdx.y;
    const float* W = (wi == 0) ? Wq : ((wi == 1) ? Wk : Wv);
    const float scale = (wi == 0) ? 0.125f * 1.44269504088896f : 1.0f;
    __shared__ short tile[64][65];
    const int t = threadIdx.x;
    #pragma unroll
    for (int i = 0; i < 16; ++i) {
        int flat = i * 256 + t;
        int kk = flat >> 6, n = flat & 63;
        tile[kk][n] = bf1(W[(size_t)(kc + kk) * HDIM + n] * scale);
    }
    __syncthreads();
    const int n = t >> 2, c0 = (t & 3) * 16;
    #pragma unroll
    for (int i = 0; i < 16; ++i)
        Wt[((size_t)wi * 64 + n) * CDIM + kc + c0 + i] = tile[c0 + i][n];
}

// ---------------------------------------------------------------------------
// Kernel 1: QKV projection, 32 rows/block (512 blocks), 2-phase pipelined
// with COUNTED vmcnt (T4): stage(next) is issued before the barrier and
// stays in flight across it -- s_waitcnt vmcnt(8) waits only for the
// previous stage's 8 loads, never draining the queue (AITER pattern).
// Outputs: Q,K row-major [t][64]; V transposed Vt[b][h][t].
// ---------------------------------------------------------------------------
__global__ __launch_bounds__(256) void qkv_kernel(
        const float* __restrict__ x, const short* __restrict__ Wt,
        short* __restrict__ Q, short* __restrict__ K, short* __restrict__ Vt) {
    __shared__ float xs[2][32 * 64];      // 2 x 8 KB, swizzled
    __shared__ short wl[2][3 * 64 * 64];  // 2 x 24 KB, swizzled
    __shared__ short ob[32 * 72];         // epilogue staging (padded)
    const int t = threadIdx.x;
    const int lane = t & 63, w = t >> 6;
    const int lr = lane & 15, lg = lane >> 4;
    const int r0 = blockIdx.x * 32;

    auto stage = [&](int buf, int kc) {   // 8 global_load_lds per thread
        #pragma unroll
        for (int i = 0; i < 2; ++i) {
            int chunk = t + 256 * i;
            int row = chunk >> 4, slot = chunk & 15;
            GLOAD16(x + (size_t)(r0 + row) * CDIM + kc + ((slot ^ (row & 7)) << 2),
                    xs[buf] + chunk * 4);
        }
        #pragma unroll
        for (int i = 0; i < 6; ++i) {
            int chunk = t + 256 * i;
            int R = chunk >> 3, slot = chunk & 7;
            GLOAD16(Wt + (size_t)R * CDIM + kc + ((slot ^ (R & 7)) << 3),
                    wl[buf] + chunk * 8);
        }
    };

    f32x4 acc[3][2];
    #pragma unroll
    for (int wi = 0; wi < 3; ++wi)
        #pragma unroll
        for (int rt = 0; rt < 2; ++rt) acc[wi][rt] = f32x4{0.f, 0.f, 0.f, 0.f};

    stage(0, 0);
    int cur = 0;
    for (int kc = 0; kc < CDIM; kc += 64) {
        if (kc + 64 < CDIM) {
            stage(cur ^ 1, kc + 64);      // 8 new loads -> 16 outstanding
            asm volatile("s_waitcnt vmcnt(8)" ::: "memory");  // cur's 8 done
        } else {
            asm volatile("s_waitcnt vmcnt(0)" ::: "memory");  // drain last
        }
        __builtin_amdgcn_s_barrier();
        asm volatile("" ::: "memory");
        const float* xsc = xs[cur];
        const short* wlc = wl[cur];

        short8 af[2][2];
        #pragma unroll
        for (int rt = 0; rt < 2; ++rt)
            #pragma unroll
            for (int ks = 0; ks < 2; ++ks) {
                int row = rt * 16 + lr;
                int s0 = ks * 8 + lg * 2;
                f32x4 a0 = *(const f32x4*)(xsc + row * 64 + (((s0)     ^ (row & 7)) << 2));
                f32x4 a1 = *(const f32x4*)(xsc + row * 64 + (((s0 + 1) ^ (row & 7)) << 2));
                uint4 uu;
                uu.x = cvtpk(a0[0], a0[1]); uu.y = cvtpk(a0[2], a0[3]);
                uu.z = cvtpk(a1[0], a1[1]); uu.w = cvtpk(a1[2], a1[3]);
                af[rt][ks] = __builtin_bit_cast(short8, uu);
            }
        #pragma unroll
        for (int wi = 0; wi < 3; ++wi)
            #pragma unroll
            for (int ks = 0; ks < 2; ++ks) {
                int R = wi * 64 + w * 16 + lr;
                short8 bfv = *(const short8*)(wlc + R * 64 + (((ks * 4 + lg) ^ (lr & 7)) << 3));
                #pragma unroll
                for (int rt = 0; rt < 2; ++rt)
                    acc[wi][rt] = __builtin_amdgcn_mfma_f32_16x16x32_bf16(
                        af[rt][ks], bfv, acc[wi][rt], 0, 0, 0);
            }
        // barrier before next iteration's stage overwrites buf cur^1:
        // NOT needed -- stage targets cur^1 only on the NEXT iteration,
        // after this barrier-separated compute; the vmcnt-barrier at the
        // top of the next iteration orders it. But LDS reads of buf cur
        // must complete before cur is re-staged two iterations later --
        // guaranteed by the intervening barrier + in-order ds issue.
        __builtin_amdgcn_s_barrier();
        cur ^= 1;
    }
    // V epilogue: C/D rows are consecutive t -> pack pairs, 8B stores to Vt[b][h][t]
    {
        const int bb = r0 >> 11, t0 = r0 & 2047;
        #pragma unroll
        for (int rt = 0; rt < 2; ++rt) {
            uint2 uv;
            uv.x = cvtpk(acc[2][rt][0], acc[2][rt][1]);
            uv.y = cvtpk(acc[2][rt][2], acc[2][rt][3]);
            *(uint2*)(Vt + ((size_t)bb * HDIM + w * 16 + lr) * TLEN + t0 + rt * 16 + lg * 4) = uv;
        }
    }
    // Q, K epilogue via LDS transpose -> coalesced short8 stores
    #pragma unroll
    for (int wi = 0; wi < 2; ++wi) {
        __syncthreads();
        #pragma unroll
        for (int rt = 0; rt < 2; ++rt)
            #pragma unroll
            for (int i = 0; i < 4; ++i)
                ob[(rt * 16 + lg * 4 + i) * 72 + w * 16 + lr] = bf1(acc[wi][rt][i]);
        __syncthreads();
        int row = t >> 3, c0 = (t & 7) * 8;
        short8 v = *(short8*)(ob + row * 72 + c0);
        short* dst = (wi == 0) ? Q : K;
        *(short8*)(dst + (size_t)(r0 + row) * HDIM + c0) = v;
    }
}

// ---------------------------------------------------------------------------
// Kernel 2: flash attention, causal, swapped QK^T (S^T = mfma(K, Q)),
// base-2 softmax. One 16-row q-tile per block, 1024 blocks = 4 blocks/CU.
// All 4 waves split the tile's kv supertiles 4-way, no barriers in loop;
// 4 partial (m,l,O^T) states merge once via LDS. Heavy tiles dispatch
// first. V loads issue BEFORE the QK MFMAs so their L2 latency hides
// under QK issue + mask + softmax.
// ---------------------------------------------------------------------------
__global__ __launch_bounds__(256, 4) void attn_kernel(
        const short* __restrict__ Q, const short* __restrict__ K,
        const short* __restrict__ Vt, float* __restrict__ O) {
    __shared__ short Ps[4][16 * 64];   // per-wave P buffer, XOR-swizzled
    __shared__ float Om[4][16 * 68];   // per-wave [q][h] partials, padded
    __shared__ float ml[4][2][16];     // per-wave {m,l}[q]
    const int t = threadIdx.x, lane = t & 63, w = t >> 6;
    const int lr = lane & 15, lg = lane >> 4;
    const int b = blockIdx.x;
    const int qi = (TLEN / 16 - 1) - blockIdx.y;   // descending: heavy first
    const int q0 = qi * 16;
    const size_t base = (size_t)b * TLEN * HDIM;
    const short* Kb = K + base;
    const short* Vb = Vt + base;    // same per-batch stride (64*2048)
    char* myPs = (char*)Ps[w];
    const int swz = (lr & 7) << 4;  // byte XOR within 128B row
    const int nsup = (q0 + 79) >> 6;

    // Q B-operand fragments: col = q = lr, k = h
    short8 qf0 = *(const short8*)(Q + base + (size_t)(q0 + lr) * HDIM + lg * 8);
    short8 qf1 = *(const short8*)(Q + base + (size_t)(q0 + lr) * HDIM + 32 + lg * 8);

    f32x4 o[4];
    #pragma unroll
    for (int ht = 0; ht < 4; ++ht) o[ht] = f32x4{0.f, 0.f, 0.f, 0.f};
    float m = -1e30f, l = 0.f;

    for (int s = w; s < nsup; s += 4) {
        const int kv0 = s * 64;
        // K fragments (A-operand rows = kv)
        short8 kf[8];
        #pragma unroll
        for (int h2 = 0; h2 < 2; ++h2)
            #pragma unroll
            for (int kt = 0; kt < 2; ++kt) {
                const short* kp = Kb + (size_t)(kv0 + h2 * 32 + kt * 16 + lr) * HDIM + lg * 8;
                kf[(h2 * 2 + kt) * 2]     = *(const short8*)kp;
                kf[(h2 * 2 + kt) * 2 + 1] = *(const short8*)(kp + 32);
            }
        // V loads issue BEFORE QK: latency hides under QK + mask + softmax
        short8 vf[8];
        #pragma unroll
        for (int h2 = 0; h2 < 2; ++h2)
            #pragma unroll
            for (int ht = 0; ht < 4; ++ht)
                vf[h2 * 4 + ht] = *(const short8*)(
                    Vb + (size_t)(ht * 16 + lr) * TLEN + kv0 + h2 * 32 + lg * 8);
        // S^T = K Q^T : rows = kv, cols = q (already in log2 units)
        f32x4 st[2][2];
        #pragma unroll
        for (int h2 = 0; h2 < 2; ++h2)
            #pragma unroll
            for (int kt = 0; kt < 2; ++kt) {
                f32x4 a = f32x4{0.f, 0.f, 0.f, 0.f};
                a = __builtin_amdgcn_mfma_f32_16x16x32_bf16(kf[(h2*2+kt)*2],     qf0, a, 0, 0, 0);
                a = __builtin_amdgcn_mfma_f32_16x16x32_bf16(kf[(h2*2+kt)*2 + 1], qf1, a, 0, 0, 0);
                st[h2][kt] = a;
            }
        if (s == nsup - 1) {              // diagonal supertile: mask kv > q
            const int q = q0 + lr;
            #pragma unroll
            for (int h2 = 0; h2 < 2; ++h2)
                #pragma unroll
                for (int kt = 0; kt < 2; ++kt)
                    #pragma unroll
                    for (int i = 0; i < 4; ++i)
                        if (kv0 + h2 * 32 + kt * 16 + lg * 4 + i > q)
                            st[h2][kt][i] = -1e30f;
        }
        // online softmax (base 2) for q-row lr: in-lane over 16 vals + 2 shfl
        float tm = -1e30f;
        #pragma unroll
        for (int h2 = 0; h2 < 2; ++h2)
            #pragma unroll
            for (int kt = 0; kt < 2; ++kt)
                #pragma unroll
                for (int i = 0; i < 4; ++i) tm = fmaxf(tm, st[h2][kt][i]);
        tm = fmaxf(tm, __shfl_xor(tm, 16));
        tm = fmaxf(tm, __shfl_xor(tm, 32));
        float mn = fmaxf(m, tm);
        float fs = EXP2(m - mn);
        m = mn;
        float ls = 0.f;
        #pragma unroll
        for (int h2 = 0; h2 < 2; ++h2)
            #pragma unroll
            for (int kt = 0; kt < 2; ++kt)
                #pragma unroll
                for (int i = 0; i < 4; ++i) {
                    float e = EXP2(st[h2][kt][i] - mn);
                    st[h2][kt][i] = e;
                    ls += e;
                }
        ls += __shfl_xor(ls, 16);
        ls += __shfl_xor(ls, 32);
        l = l * fs + ls;
        #pragma unroll
        for (int ht = 0; ht < 4; ++ht)
            #pragma unroll
            for (int i = 0; i < 4; ++i) o[ht][i] *= fs;
        // pack P -> per-wave swizzled LDS (row = q = lr), then B-frag reads
        #pragma unroll
        for (int h2 = 0; h2 < 2; ++h2)
            #pragma unroll
            for (int kt = 0; kt < 2; ++kt) {
                uint2 u;
                u.x = cvtpk(st[h2][kt][0], st[h2][kt][1]);
                u.y = cvtpk(st[h2][kt][2], st[h2][kt][3]);
                *(uint2*)(myPs + lr * 128 + ((h2 * 64 + kt * 32 + lg * 8) ^ swz)) = u;
            }
        short8 pb0 = *(short8*)(myPs + lr * 128 + ((lg * 16) ^ swz));
        short8 pb1 = *(short8*)(myPs + lr * 128 + ((64 + lg * 16) ^ swz));
        // O^T += V^T P
        #pragma unroll
        for (int h2 = 0; h2 < 2; ++h2) {
            short8 pb = h2 ? pb1 : pb0;
            #pragma unroll
            for (int ht = 0; ht < 4; ++ht)
                o[ht] = __builtin_amdgcn_mfma_f32_16x16x32_bf16(
                    vf[h2 * 4 + ht], pb, o[ht], 0, 0, 0);
        }
    }
    // write partial state
    {
        float* om = Om[w];
        #pragma unroll
        for (int ht = 0; ht < 4; ++ht)
            *(f32x4*)(om + lr * 68 + ht * 16 + lg * 4) = o[ht];
        if (lg == 0) {
            ml[w][0][lr] = m;
            ml[w][1][lr] = l;
        }
    }
    __syncthreads();
    // merge 4 partials: thread (w,lane) handles q = lr, h = w*16 + lg*4 ..
    {
        float mp[4], fp[4];
        float mm = -1e30f;
        #pragma unroll
        for (int p = 0; p < 4; ++p) { mp[p] = ml[p][0][lr]; mm = fmaxf(mm, mp[p]); }
        float lsum = 0.f;
        #pragma unroll
        for (int p = 0; p < 4; ++p) {
            fp[p] = EXP2(mp[p] - mm);
            lsum += ml[p][1][lr] * fp[p];
        }
        float inv = 1.0f / lsum;
        const int off = lr * 68 + w * 16 + lg * 4;
        f32x4 r = f32x4{0.f, 0.f, 0.f, 0.f};
        #pragma unroll
        for (int p = 0; p < 4; ++p) {
            f32x4 v = *(const f32x4*)(&Om[p][off]);
            #pragma unroll
            for (int i = 0; i < 4; ++i) r[i] += v[i] * fp[p];
        }
        #pragma unroll
        for (int i = 0; i < 4; ++i) r[i] *= inv;
        *(f32x4*)(O + base + (size_t)(q0 + lr) * HDIM + w * 16 + lg * 4) = r;
    }
}

// ---------------------------------------------------------------------------
extern "C" void kernel_launch(void* const* d_in, const int* in_sizes, int n_in,
                              void* d_out, int out_size, void* d_ws, size_t ws_size,
                              hipStream_t stream) {
    const float* x  = (const float*)d_in[0];
    const float* Wq = (const float*)d_in[1];
    const float* Wk = (const float*)d_in[2];
    const float* Wv = (const float*)d_in[3];
    float* out = (float*)d_out;

    char* ws = (char*)d_ws;
    short* Q  = (short*)(ws);
    short* K  = (short*)(ws + (size_t)2 * 1024 * 1024);
    short* Vt = (short*)(ws + (size_t)4 * 1024 * 1024);
    short* Wt = (short*)(ws + (size_t)6 * 1024 * 1024);

    wt_kernel<<<dim3(16, 3), 256, 0, stream>>>(Wq, Wk, Wv, Wt);
    qkv_kernel<<<BT / 32, 256, 0, stream>>>(x, Wt, Q, K, Vt);
    attn_kernel<<<dim3(BATCH, TLEN / 16), 256, 0, stream>>>(Q, K, Vt, out);
}

// Round 8
// 139.624 us; speedup vs baseline: 1.0867x; 1.0764x over previous
//
#include <hip/hip_runtime.h>
#include <hip/hip_bf16.h>

// Problem constants
#define BATCH 8
#define TLEN 2048
#define CDIM 1024
#define HDIM 64
#define BT (BATCH * TLEN)   // 16384

typedef __attribute__((ext_vector_type(8))) short short8;
typedef __attribute__((ext_vector_type(4))) float f32x4;

#define GLOAD16(gsrc, lds) __builtin_amdgcn_global_load_lds( \
    (const __attribute__((address_space(1))) void*)(gsrc),   \
    (__attribute__((address_space(3))) void*)(lds), 16, 0, 0)

#if __has_builtin(__builtin_amdgcn_exp2f)
#define EXP2(x) __builtin_amdgcn_exp2f(x)
#else
#define EXP2(x) exp2f(x)
#endif

// round-to-nearest-even f32 -> bf16 (bit pattern)
__device__ inline unsigned bfbits(float f) {
    unsigned u = __builtin_bit_cast(unsigned, f);
    return (u + 0x7fffu + ((u >> 16) & 1u)) >> 16;
}
__device__ inline short bf1(float f) { return (short)bfbits(f); }
// packed f32x2 -> bf16x2 via HW instruction (src0 -> low half)
__device__ inline unsigned cvtpk(float lo, float hi) {
    unsigned r;
    asm("v_cvt_pk_bf16_f32 %0, %1, %2" : "=v"(r) : "v"(lo), "v"(hi));
    return r;
}

// ---------------------------------------------------------------------------
// Kernel 0: transpose + bf16-cast weights. Wt[3][64 n][1024 k] = W[k][n].
// Folds attention scale AND log2(e) into Wq (softmax runs in base 2).
// ---------------------------------------------------------------------------
__global__ __launch_bounds__(256) void wt_kernel(
        const float* __restrict__ Wq, const float* __restrict__ Wk,
        const float* __restrict__ Wv, short* __restrict__ Wt) {
    const int kc = blockIdx.x * 64;
    const int wi = blockIdx.y;
    const float* W = (wi == 0) ? Wq : ((wi == 1) ? Wk : Wv);
    const float scale = (wi == 0) ? 0.125f * 1.44269504088896f : 1.0f;
    __shared__ short tile[64][65];
    const int t = threadIdx.x;
    #pragma unroll
    for (int i = 0; i < 16; ++i) {
        int flat = i * 256 + t;
        int kk = flat >> 6, n = flat & 63;
        tile[kk][n] = bf1(W[(size_t)(kc + kk) * HDIM + n] * scale);
    }
    __syncthreads();
    const int n = t >> 2, c0 = (t & 3) * 16;
    #pragma unroll
    for (int i = 0; i < 16; ++i)
        Wt[((size_t)wi * 64 + n) * CDIM + kc + c0 + i] = tile[c0 + i][n];
}

// ---------------------------------------------------------------------------
// Kernel 1: QKV projection, 32 rows/block (512 blocks), 2-phase pipelined
// with COUNTED vmcnt (T4): stage(next) issued before the barrier stays in
// flight across it. Outputs: Q,K row-major [t][64]; V transposed Vt[b][h][t].
// ---------------------------------------------------------------------------
__global__ __launch_bounds__(256) void qkv_kernel(
        const float* __restrict__ x, const short* __restrict__ Wt,
        short* __restrict__ Q, short* __restrict__ K, short* __restrict__ Vt) {
    __shared__ float xs[2][32 * 64];      // 2 x 8 KB, swizzled
    __shared__ short wl[2][3 * 64 * 64];  // 2 x 24 KB, swizzled
    __shared__ short ob[32 * 72];         // epilogue staging (padded)
    const int t = threadIdx.x;
    const int lane = t & 63, w = t >> 6;
    const int lr = lane & 15, lg = lane >> 4;
    const int r0 = blockIdx.x * 32;

    auto stage = [&](int buf, int kc) {   // 8 global_load_lds per thread
        #pragma unroll
        for (int i = 0; i < 2; ++i) {
            int chunk = t + 256 * i;
            int row = chunk >> 4, slot = chunk & 15;
            GLOAD16(x + (size_t)(r0 + row) * CDIM + kc + ((slot ^ (row & 7)) << 2),
                    xs[buf] + chunk * 4);
        }
        #pragma unroll
        for (int i = 0; i < 6; ++i) {
            int chunk = t + 256 * i;
            int R = chunk >> 3, slot = chunk & 7;
            GLOAD16(Wt + (size_t)R * CDIM + kc + ((slot ^ (R & 7)) << 3),
                    wl[buf] + chunk * 8);
        }
    };

    f32x4 acc[3][2];
    #pragma unroll
    for (int wi = 0; wi < 3; ++wi)
        #pragma unroll
        for (int rt = 0; rt < 2; ++rt) acc[wi][rt] = f32x4{0.f, 0.f, 0.f, 0.f};

    stage(0, 0);
    int cur = 0;
    for (int kc = 0; kc < CDIM; kc += 64) {
        if (kc + 64 < CDIM) {
            stage(cur ^ 1, kc + 64);      // 8 new loads -> 16 outstanding
            asm volatile("s_waitcnt vmcnt(8)" ::: "memory");  // cur's 8 done
        } else {
            asm volatile("s_waitcnt vmcnt(0)" ::: "memory");  // drain last
        }
        __builtin_amdgcn_s_barrier();
        asm volatile("" ::: "memory");
        const float* xsc = xs[cur];
        const short* wlc = wl[cur];

        short8 af[2][2];
        #pragma unroll
        for (int rt = 0; rt < 2; ++rt)
            #pragma unroll
            for (int ks = 0; ks < 2; ++ks) {
                int row = rt * 16 + lr;
                int s0 = ks * 8 + lg * 2;
                f32x4 a0 = *(const f32x4*)(xsc + row * 64 + (((s0)     ^ (row & 7)) << 2));
                f32x4 a1 = *(const f32x4*)(xsc + row * 64 + (((s0 + 1) ^ (row & 7)) << 2));
                uint4 uu;
                uu.x = cvtpk(a0[0], a0[1]); uu.y = cvtpk(a0[2], a0[3]);
                uu.z = cvtpk(a1[0], a1[1]); uu.w = cvtpk(a1[2], a1[3]);
                af[rt][ks] = __builtin_bit_cast(short8, uu);
            }
        #pragma unroll
        for (int wi = 0; wi < 3; ++wi)
            #pragma unroll
            for (int ks = 0; ks < 2; ++ks) {
                int R = wi * 64 + w * 16 + lr;
                short8 bfv = *(const short8*)(wlc + R * 64 + (((ks * 4 + lg) ^ (lr & 7)) << 3));
                #pragma unroll
                for (int rt = 0; rt < 2; ++rt)
                    acc[wi][rt] = __builtin_amdgcn_mfma_f32_16x16x32_bf16(
                        af[rt][ks], bfv, acc[wi][rt], 0, 0, 0);
            }
        __builtin_amdgcn_s_barrier();
        cur ^= 1;
    }
    // V epilogue: C/D rows are consecutive t -> pack pairs, 8B stores to Vt[b][h][t]
    {
        const int bb = r0 >> 11, t0 = r0 & 2047;
        #pragma unroll
        for (int rt = 0; rt < 2; ++rt) {
            uint2 uv;
            uv.x = cvtpk(acc[2][rt][0], acc[2][rt][1]);
            uv.y = cvtpk(acc[2][rt][2], acc[2][rt][3]);
            *(uint2*)(Vt + ((size_t)bb * HDIM + w * 16 + lr) * TLEN + t0 + rt * 16 + lg * 4) = uv;
        }
    }
    // Q, K epilogue via LDS transpose -> coalesced short8 stores
    #pragma unroll
    for (int wi = 0; wi < 2; ++wi) {
        __syncthreads();
        #pragma unroll
        for (int rt = 0; rt < 2; ++rt)
            #pragma unroll
            for (int i = 0; i < 4; ++i)
                ob[(rt * 16 + lg * 4 + i) * 72 + w * 16 + lr] = bf1(acc[wi][rt][i]);
        __syncthreads();
        int row = t >> 3, c0 = (t & 7) * 8;
        short8 v = *(short8*)(ob + row * 72 + c0);
        short* dst = (wi == 0) ? Q : K;
        *(short8*)(dst + (size_t)(r0 + row) * HDIM + c0) = v;
    }
}

// ---------------------------------------------------------------------------
// Kernel 2: flash attention, causal, swapped QK^T, base-2 softmax.
// One 16-row q-tile per block (1024 blocks, 4/CU); 4 waves split kv 4-way,
// no barriers in the loop. NEW: V supertiles are staged into a PER-WAVE
// 8KB LDS buffer via coalesced global_load_lds (8 rows x 128B per instr,
// XOR-pre-swizzled source, rule #21) instead of 4KB-strided register
// gathers -- 8x fewer L2 lines. vf frags are ds_read_b128 (swizzled) into
// regs, then V(s+4) staging issues and hides under softmax+pack+PV.
// Merge buffers alias the V arena (dead after the loop).
// ---------------------------------------------------------------------------
__global__ __launch_bounds__(256, 4) void attn_kernel(
        const short* __restrict__ Q, const short* __restrict__ K,
        const short* __restrict__ Vt, float* __restrict__ O) {
    __shared__ float arena[4][2048];   // 32 KB: per-wave V staging / merge Om+ml
    __shared__ short Ps[4][16 * 64];   // per-wave P buffer, XOR-swizzled (8 KB)
    const int t = threadIdx.x, lane = t & 63, w = t >> 6;
    const int lr = lane & 15, lg = lane >> 4;
    const int b = blockIdx.x;
    const int qi = (TLEN / 16 - 1) - blockIdx.y;   // descending: heavy first
    const int q0 = qi * 16;
    const size_t base = (size_t)b * TLEN * HDIM;
    const short* Kb = K + base;
    const short* Vb = Vt + base;    // same per-batch stride (64*2048)
    char* myPs = (char*)Ps[w];
    char* vbuf = (char*)arena[w];   // 8 KB per-wave V tile
    const int swz = (lr & 7) << 4;  // byte XOR within 128B row (P buffer)
    const int nsup = (q0 + 79) >> 6;
    const int r8 = lane >> 3, c8 = lane & 7;   // V staging coords

    // stage V supertile s into vbuf: 8 instrs x (8 rows x 128B), source
    // column pre-swizzled by row so swizzled ds_read_b128 is bank-optimal
    auto stageV = [&](int s) {
        const int kv0 = s * 64;
        #pragma unroll
        for (int j = 0; j < 8; ++j)
            GLOAD16(Vb + (size_t)(j * 8 + r8) * TLEN + kv0 + ((c8 ^ r8) << 3),
                    vbuf + j * 1024 + lane * 16);
    };

    // Q B-operand fragments: col = q = lr, k = h
    short8 qf0 = *(const short8*)(Q + base + (size_t)(q0 + lr) * HDIM + lg * 8);
    short8 qf1 = *(const short8*)(Q + base + (size_t)(q0 + lr) * HDIM + 32 + lg * 8);

    f32x4 o[4];
    #pragma unroll
    for (int ht = 0; ht < 4; ++ht) o[ht] = f32x4{0.f, 0.f, 0.f, 0.f};
    float m = -1e30f, l = 0.f;

    if (w < nsup) stageV(w);
    for (int s = w; s < nsup; s += 4) {
        const int kv0 = s * 64;
        // K fragments direct (contiguous 2KB blocks per set -> coalesced)
        short8 kf[8];
        #pragma unroll
        for (int h2 = 0; h2 < 2; ++h2)
            #pragma unroll
            for (int kt = 0; kt < 2; ++kt) {
                const short* kp = Kb + (size_t)(kv0 + h2 * 32 + kt * 16 + lr) * HDIM + lg * 8;
                kf[(h2 * 2 + kt) * 2]     = *(const short8*)kp;
                kf[(h2 * 2 + kt) * 2 + 1] = *(const short8*)(kp + 32);
            }
        // wait: K regs arrived => V(s) (issued earlier, in-order) is in LDS
        asm volatile("s_waitcnt vmcnt(0)" ::: "memory");
        __builtin_amdgcn_sched_barrier(0);
        // extract all V fragments from LDS (swizzled read)
        short8 vf[8];
        #pragma unroll
        for (int h2 = 0; h2 < 2; ++h2)
            #pragma unroll
            for (int ht = 0; ht < 4; ++ht) {
                int row = ht * 16 + lr;
                vf[h2 * 4 + ht] = *(const short8*)(
                    vbuf + row * 128 + (((h2 * 4 + lg) ^ (lr & 7)) << 4));
            }
        asm volatile("s_waitcnt lgkmcnt(0)" ::: "memory");
        __builtin_amdgcn_sched_barrier(0);
        // vf settled in regs -> safe to overwrite vbuf with next supertile
        if (s + 4 < nsup) stageV(s + 4);

        // S^T = K Q^T : rows = kv, cols = q (log2 units)
        f32x4 st[2][2];
        #pragma unroll
        for (int h2 = 0; h2 < 2; ++h2)
            #pragma unroll
            for (int kt = 0; kt < 2; ++kt) {
                f32x4 a = f32x4{0.f, 0.f, 0.f, 0.f};
                a = __builtin_amdgcn_mfma_f32_16x16x32_bf16(kf[(h2*2+kt)*2],     qf0, a, 0, 0, 0);
                a = __builtin_amdgcn_mfma_f32_16x16x32_bf16(kf[(h2*2+kt)*2 + 1], qf1, a, 0, 0, 0);
                st[h2][kt] = a;
            }
        if (s == nsup - 1) {              // diagonal supertile: mask kv > q
            const int q = q0 + lr;
            #pragma unroll
            for (int h2 = 0; h2 < 2; ++h2)
                #pragma unroll
                for (int kt = 0; kt < 2; ++kt)
                    #pragma unroll
                    for (int i = 0; i < 4; ++i)
                        if (kv0 + h2 * 32 + kt * 16 + lg * 4 + i > q)
                            st[h2][kt][i] = -1e30f;
        }
        // online softmax (base 2) for q-row lr: in-lane over 16 vals + 2 shfl
        float tm = -1e30f;
        #pragma unroll
        for (int h2 = 0; h2 < 2; ++h2)
            #pragma unroll
            for (int kt = 0; kt < 2; ++kt)
                #pragma unroll
                for (int i = 0; i < 4; ++i) tm = fmaxf(tm, st[h2][kt][i]);
        tm = fmaxf(tm, __shfl_xor(tm, 16));
        tm = fmaxf(tm, __shfl_xor(tm, 32));
        float mn = fmaxf(m, tm);
        float fs = EXP2(m - mn);
        m = mn;
        float ls = 0.f;
        #pragma unroll
        for (int h2 = 0; h2 < 2; ++h2)
            #pragma unroll
            for (int kt = 0; kt < 2; ++kt)
                #pragma unroll
                for (int i = 0; i < 4; ++i) {
                    float e = EXP2(st[h2][kt][i] - mn);
                    st[h2][kt][i] = e;
                    ls += e;
                }
        ls += __shfl_xor(ls, 16);
        ls += __shfl_xor(ls, 32);
        l = l * fs + ls;
        #pragma unroll
        for (int ht = 0; ht < 4; ++ht)
            #pragma unroll
            for (int i = 0; i < 4; ++i) o[ht][i] *= fs;
        // pack P -> per-wave swizzled LDS (row = q = lr), then B-frag reads
        #pragma unroll
        for (int h2 = 0; h2 < 2; ++h2)
            #pragma unroll
            for (int kt = 0; kt < 2; ++kt) {
                uint2 u;
                u.x = cvtpk(st[h2][kt][0], st[h2][kt][1]);
                u.y = cvtpk(st[h2][kt][2], st[h2][kt][3]);
                *(uint2*)(myPs + lr * 128 + ((h2 * 64 + kt * 32 + lg * 8) ^ swz)) = u;
            }
        short8 pb0 = *(short8*)(myPs + lr * 128 + ((lg * 16) ^ swz));
        short8 pb1 = *(short8*)(myPs + lr * 128 + ((64 + lg * 16) ^ swz));
        // O^T += V^T P
        #pragma unroll
        for (int h2 = 0; h2 < 2; ++h2) {
            short8 pb = h2 ? pb1 : pb0;
            #pragma unroll
            for (int ht = 0; ht < 4; ++ht)
                o[ht] = __builtin_amdgcn_mfma_f32_16x16x32_bf16(
                    vf[h2 * 4 + ht], pb, o[ht], 0, 0, 0);
        }
    }
    __syncthreads();   // all waves done with V arena -> reuse for merge
    // merge buffers alias the arena
    float* Om = &arena[0][0];            // [4][16*68] = 17408 B
    float* ml = &arena[0][0] + 4 * 16 * 68;   // [4][2][16] = 512 B
    {
        float* om = Om + w * 16 * 68;
        #pragma unroll
        for (int ht = 0; ht < 4; ++ht)
            *(f32x4*)(om + lr * 68 + ht * 16 + lg * 4) = o[ht];
        if (lg == 0) {
            ml[(w * 2 + 0) * 16 + lr] = m;
            ml[(w * 2 + 1) * 16 + lr] = l;
        }
    }
    __syncthreads();
    // merge 4 partials: thread (w,lane) handles q = lr, h = w*16 + lg*4 ..
    {
        float mp[4], fp[4];
        float mm = -1e30f;
        #pragma unroll
        for (int p = 0; p < 4; ++p) { mp[p] = ml[(p * 2 + 0) * 16 + lr]; mm = fmaxf(mm, mp[p]); }
        float lsum = 0.f;
        #pragma unroll
        for (int p = 0; p < 4; ++p) {
            fp[p] = EXP2(mp[p] - mm);
            lsum += ml[(p * 2 + 1) * 16 + lr] * fp[p];
        }
        float inv = 1.0f / lsum;
        const int off = lr * 68 + w * 16 + lg * 4;
        f32x4 r = f32x4{0.f, 0.f, 0.f, 0.f};
        #pragma unroll
        for (int p = 0; p < 4; ++p) {
            f32x4 v = *(const f32x4*)(Om + p * 16 * 68 + off);
            #pragma unroll
            for (int i = 0; i < 4; ++i) r[i] += v[i] * fp[p];
        }
        #pragma unroll
        for (int i = 0; i < 4; ++i) r[i] *= inv;
        *(f32x4*)(O + base + (size_t)(q0 + lr) * HDIM + w * 16 + lg * 4) = r;
    }
}

// ---------------------------------------------------------------------------
extern "C" void kernel_launch(void* const* d_in, const int* in_sizes, int n_in,
                              void* d_out, int out_size, void* d_ws, size_t ws_size,
                              hipStream_t stream) {
    const float* x  = (const float*)d_in[0];
    const float* Wq = (const float*)d_in[1];
    const float* Wk = (const float*)d_in[2];
    const float* Wv = (const float*)d_in[3];
    float* out = (float*)d_out;

    char* ws = (char*)d_ws;
    short* Q  = (short*)(ws);
    short* K  = (short*)(ws + (size_t)2 * 1024 * 1024);
    short* Vt = (short*)(ws + (size_t)4 * 1024 * 1024);
    short* Wt = (short*)(ws + (size_t)6 * 1024 * 1024);

    wt_kernel<<<dim3(16, 3), 256, 0, stream>>>(Wq, Wk, Wv, Wt);
    qkv_kernel<<<BT / 32, 256, 0, stream>>>(x, Wt, Q, K, Vt);
    attn_kernel<<<dim3(BATCH, TLEN / 16), 256, 0, stream>>>(Q, K, Vt, out);
}